// Round 12
// baseline (238.041 us; speedup 1.0000x reference)
//
#include <hip/hip_runtime.h>
#include <hip/hip_bf16.h>
#include <stdint.h>

#define BATCH  512
#define INPUT  20000
#define KPAD   20032     // INPUT padded to multiple of 64 (zero-filled tail)
#define NPADE  20224     // emb rows padded to multiple of 256 (zero-filled)
#define HIDDEN 1024
#define EMBED  512
#define NOUT   2048

typedef __attribute__((ext_vector_type(8))) __bf16 bf16x8;
typedef __attribute__((ext_vector_type(8))) unsigned short u16x8;
typedef __attribute__((ext_vector_type(4))) unsigned short u16x4;
typedef __attribute__((ext_vector_type(4))) float f32x4;

static __device__ __forceinline__ unsigned short f2bf(float f) {
  uint32_t u = __builtin_bit_cast(uint32_t, f);
  u += 0x7fffu + ((u >> 16) & 1u);          // round-to-nearest-even
  return (unsigned short)(u >> 16);
}

// async global->LDS (used by the small combiner GEMM)
static __device__ __forceinline__ void g2l16(const unsigned short* g, unsigned short* l) {
  __builtin_amdgcn_global_load_lds(
      (const __attribute__((address_space(1))) void*)g,
      (__attribute__((address_space(3))) void*)l, 16, 0, 0);
}

#define MFMA(a, b, c) __builtin_amdgcn_mfma_f32_16x16x32_bf16((a), (b), (c), 0, 0, 0)

// ============ Et barrier-free streaming GEMM ============
// C[h,g] = bf16(lrelu(Wemb[h,:]·embb[g,:] + b_em[h])), M=1024(h), N=20224(g), K=512.
// Per block: A = 64 Wemb rows x 512 staged ONCE into swizzled LDS (64 KB), then a
// BARRIER-FREE inner loop: B fragments stream global->reg (embb rows; 4 lanes of a
// k-chunk group read contiguous 64B), 16 k-steps x 16 MFMA, acc[4][4]/wave.
// No __syncthreads in the hot loop => compiler pipelines loads freely; 2 blocks/CU
// (LDS-capped) give wave-level overlap. XCD decode: the 16 m-siblings of each
// 256-gene panel share one XCD's L2 (2.6 MB resident).
__global__ __launch_bounds__(256, 2) void et_stream(
    const unsigned short* __restrict__ Wemb, const unsigned short* __restrict__ embb,
    const float* __restrict__ bias, unsigned short* __restrict__ Et)
{
  __shared__ __align__(16) unsigned short As[64 * 512];   // 64 KB

  const int b = blockIdx.x;
  const int xcd = b & 7, rank = b >> 3;      // rank 0..159
  const int mt = rank & 15;                  // m-tile 0..15
  const int q  = rank >> 4;                  // 0..9
  const int nidx = xcd + 8 * q;              // n-tile 0..87
  if (nidx >= 79) return;
  const int m0 = mt * 64, n0 = nidx * 256;

  const int tid = threadIdx.x;
  const int l = tid & 63, w = tid >> 6;
  const int lr = l & 15, lkc = l >> 4;

  // ---- stage A once: 64 rows x 64 chunks (16B); swizzle chunk' = chunk ^ (row&7) ----
#pragma unroll
  for (int i = 0; i < 16; ++i) {
    int flat = i * 256 + tid;
    int row = flat >> 6, ch = flat & 63;
    u16x8 v = *reinterpret_cast<const u16x8*>(Wemb + (size_t)(m0 + row) * EMBED + ch * 8);
    *reinterpret_cast<u16x8*>(As + row * EMBED + ((ch ^ (row & 7)) << 3)) = v;
  }
  __syncthreads();                            // the ONLY barrier

  const unsigned short* bbase = embb + (size_t)(n0 + w * 64 + lr) * EMBED + lkc * 8;

  f32x4 acc[4][4] = {};
#pragma unroll
  for (int ks = 0; ks < 16; ++ks) {
    bf16x8 bfr[4], a[4];
#pragma unroll
    for (int ni = 0; ni < 4; ++ni)
      bfr[ni] = *reinterpret_cast<const bf16x8*>(bbase + (size_t)(ni * 16) * EMBED + ks * 32);
#pragma unroll
    for (int mi = 0; mi < 4; ++mi)
      a[mi] = *reinterpret_cast<const bf16x8*>(
          As + (mi * 16 + lr) * EMBED + (((ks * 4 + lkc) ^ (lr & 7)) << 3));
    __builtin_amdgcn_s_setprio(1);
#pragma unroll
    for (int mi = 0; mi < 4; ++mi)
#pragma unroll
      for (int ni = 0; ni < 4; ++ni)
        acc[mi][ni] = MFMA(a[mi], bfr[ni], acc[mi][ni]);
    __builtin_amdgcn_s_setprio(0);
  }

  // C/D layout: col = lane&15, row = (lane>>4)*4 + reg  [m89/m91]
  const int rb_ = (l >> 4) * 4;
#pragma unroll
  for (int mi = 0; mi < 4; ++mi)
#pragma unroll
    for (int ni = 0; ni < 4; ++ni)
#pragma unroll
      for (int j = 0; j < 4; ++j) {
        int m = m0 + mi * 16 + rb_ + j;
        int n = n0 + w * 64 + ni * 16 + lr;
        if (n < KPAD) {
          float t2 = acc[mi][ni][j] + bias[m];
          t2 = t2 > 0.f ? t2 : 0.01f * t2;
          Et[(size_t)m * KPAD + n] = (n < INPUT) ? f2bf(t2) : (unsigned short)0;
        }
      }
}

// ====== 128x256-tile, 4-wave, 2-blocks/CU, reg-staged GEMM (BK=32, 48KB LDS) ======
// (unchanged from R11 — fused split-K only). NEVER set min-waves > 2 here (R10 spill).
template<int EPI>
__global__ __launch_bounds__(256, 2) void gemmQ(
    const unsigned short* __restrict__ A0p, const unsigned short* __restrict__ B0p,
    const unsigned short* __restrict__ A1p, const unsigned short* __restrict__ B1p,
    int lda, int ldb,
    const float* __restrict__ bias,
    void* __restrict__ Cp, int ldc,
    int Nv, int Nw, int K, int kChunk)
{
  __shared__ __align__(16) unsigned short AsW[2 * 128 * 32];  // 16 KB
  __shared__ __align__(16) unsigned short BsW[2 * 256 * 32];  // 32 KB

  const int b = blockIdx.x;
  int m0, n0, z = 0, which = 0;
  if (EPI == 1) {
    int g = ((b >> 7) << 3) | (b & 7);   // 0..31, on XCD g%8
    int j = (b >> 3) & 15;               // member 0..15
    which = g >> 4; z = g & 15;
    m0 = (j & 3) * 128;
    n0 = (j >> 2) * 256;
  } else {
    int xcd = b & 7, r = b >> 3;
    int m = r / 10, q = r - m * 10;
    int nidx = xcd + 8 * q;
    if (nidx >= 79) return;
    m0 = m * 128;
    n0 = nidx * 256;
  }
  const unsigned short* Ap = which ? A1p : A0p;
  const unsigned short* Bp = which ? B1p : B0p;

  const int k0   = z * kChunk;
  const int kend = min(K, k0 + kChunk);
  const int nt   = (kend - k0) >> 5;     // BK=32

  const int tid = threadIdx.x;
  const int l = tid & 63, w = tid >> 6;
  const int srow = tid >> 2;
  const int sc8  = tid & 3;
  const unsigned short* agl = Ap + (size_t)(m0 + srow) * lda + k0 + sc8 * 8;
  const unsigned short* bgl = Bp + (size_t)(n0 + srow) * ldb + k0 + sc8 * 8;
  const int swc = ((sc8 ^ ((srow >> 1) & 3)) << 3);

  const int lr = l & 15, lkc = l >> 4;
  const int ck = ((lkc ^ ((lr >> 1) & 3)) << 3);

  f32x4 acc[8][4] = {};
  u16x8 ra0, ra1, rb0, rb1, rb2, rb3;

#define LOADT(dk)                                                           \
  do {                                                                      \
    ra0 = *reinterpret_cast<const u16x8*>(agl + (size_t)0   * lda + (dk)); \
    ra1 = *reinterpret_cast<const u16x8*>(agl + (size_t)64  * lda + (dk)); \
    rb0 = *reinterpret_cast<const u16x8*>(bgl + (size_t)0   * ldb + (dk)); \
    rb1 = *reinterpret_cast<const u16x8*>(bgl + (size_t)64  * ldb + (dk)); \
    rb2 = *reinterpret_cast<const u16x8*>(bgl + (size_t)128 * ldb + (dk)); \
    rb3 = *reinterpret_cast<const u16x8*>(bgl + (size_t)192 * ldb + (dk)); \
  } while (0)

#define WRITET(BUF)                                                         \
  do {                                                                      \
    *reinterpret_cast<u16x8*>(AsW + (BUF)*4096 + (srow      ) * 32 + swc) = ra0; \
    *reinterpret_cast<u16x8*>(AsW + (BUF)*4096 + (srow +  64) * 32 + swc) = ra1; \
    *reinterpret_cast<u16x8*>(BsW + (BUF)*8192 + (srow      ) * 32 + swc) = rb0; \
    *reinterpret_cast<u16x8*>(BsW + (BUF)*8192 + (srow +  64) * 32 + swc) = rb1; \
    *reinterpret_cast<u16x8*>(BsW + (BUF)*8192 + (srow + 128) * 32 + swc) = rb2; \
    *reinterpret_cast<u16x8*>(BsW + (BUF)*8192 + (srow + 192) * 32 + swc) = rb3; \
  } while (0)

  LOADT(0);
  WRITET(0);
  __syncthreads();

  for (int t = 0; t < nt; ++t) {
    const int buf = t & 1, nb = buf ^ 1;
    if (t + 1 < nt) LOADT((t + 1) << 5);
    __builtin_amdgcn_sched_barrier(0);

    bf16x8 a[8], bfr[4];
#pragma unroll
    for (int mi = 0; mi < 8; ++mi)
      a[mi] = *reinterpret_cast<const bf16x8*>(AsW + buf * 4096 + (mi * 16 + lr) * 32 + ck);
#pragma unroll
    for (int ni = 0; ni < 4; ++ni)
      bfr[ni] = *reinterpret_cast<const bf16x8*>(
          BsW + buf * 8192 + (w * 64 + ni * 16 + lr) * 32 + ck);

    __builtin_amdgcn_s_setprio(1);
#pragma unroll
    for (int mi = 0; mi < 8; ++mi)
#pragma unroll
      for (int ni = 0; ni < 4; ++ni)
        acc[mi][ni] = MFMA(a[mi], bfr[ni], acc[mi][ni]);
    __builtin_amdgcn_s_setprio(0);

    if (t + 1 < nt) WRITET(nb);
    __syncthreads();
  }
#undef LOADT
#undef WRITET

  const int rb_ = (l >> 4) * 4;
#pragma unroll
  for (int mi = 0; mi < 8; ++mi)
#pragma unroll
    for (int ni = 0; ni < 4; ++ni)
#pragma unroll
      for (int j = 0; j < 4; ++j) {
        int m = m0 + mi * 16 + rb_ + j;
        int n = n0 + w * 64 + ni * 16 + lr;
        float v = acc[mi][ni][j];
        if (EPI == 0) {
          if (n < Nw) {
            float t2 = v + bias[m];
            t2 = t2 > 0.f ? t2 : 0.01f * t2;
            reinterpret_cast<unsigned short*>(Cp)[(size_t)m * ldc + n] =
                (n < Nv) ? f2bf(t2) : (unsigned short)0;
          }
        } else {
          reinterpret_cast<float*>(Cp)[(size_t)z * (BATCH * NOUT) + (size_t)m * ldc +
                                       which * 1024 + n] = v;
        }
      }
}

// ===== 128x128-tile m97-style GEMM (combiner only) =====
template<int EPI>
__global__ __launch_bounds__(256) void gemm97(
    const unsigned short* __restrict__ A, const unsigned short* __restrict__ B,
    int lda, int ldb,
    const float* __restrict__ bias,
    void* __restrict__ Cp, int ldc, int pstride,
    int M, int N, int Nw, int K, int kChunk)
{
  __shared__ __align__(16) unsigned short As[128 * 64];
  __shared__ __align__(16) unsigned short Bs[128 * 64];

  const int z = blockIdx.z;
  const int m0 = blockIdx.y * 128, n0 = blockIdx.x * 128;
  const int k0   = z * kChunk;
  const int kend = min(K, k0 + kChunk);
  const int tid = threadIdx.x;
  const int l = tid & 63, w = tid >> 6;

  const int srow = w * 32 + (l >> 3);
  const int scol = (l & 7) * 8;
  const unsigned short* ag = A + (size_t)(m0 + srow) * lda + scol;
  const unsigned short* bg = B + (size_t)(n0 + srow) * ldb + scol;

  const int wm = (w >> 1) * 64, wn = (w & 1) * 64;
  const int lr = l & 15, lk = (l >> 4) * 8;

  f32x4 acc[4][4] = {};

  for (int kb = k0; kb < kend; kb += 64) {
#pragma unroll
    for (int j = 0; j < 4; ++j)
      g2l16(ag + (size_t)j * 8 * lda + kb, As + (w * 32 + j * 8) * 64);
#pragma unroll
    for (int j = 0; j < 4; ++j)
      g2l16(bg + (size_t)j * 8 * ldb + kb, Bs + (w * 32 + j * 8) * 64);
    __syncthreads();
#pragma unroll
    for (int ks = 0; ks < 2; ++ks) {
      bf16x8 a[4], b2[4];
#pragma unroll
      for (int i = 0; i < 4; ++i)
        a[i] = *reinterpret_cast<const bf16x8*>(&As[(wm + i * 16 + lr) * 64 + ks * 32 + lk]);
#pragma unroll
      for (int i = 0; i < 4; ++i)
        b2[i] = *reinterpret_cast<const bf16x8*>(&Bs[(wn + i * 16 + lr) * 64 + ks * 32 + lk]);
#pragma unroll
      for (int mi = 0; mi < 4; ++mi)
#pragma unroll
        for (int ni = 0; ni < 4; ++ni)
          acc[mi][ni] = MFMA(a[mi], b2[ni], acc[mi][ni]);
    }
    __syncthreads();
  }

  const int rb = (l >> 4) * 4;
#pragma unroll
  for (int mi = 0; mi < 4; ++mi) {
#pragma unroll
    for (int ni = 0; ni < 4; ++ni) {
#pragma unroll
      for (int j = 0; j < 4; ++j) {
        int m = m0 + wm + mi * 16 + rb + j;
        int n = n0 + wn + ni * 16 + lr;
        float v = acc[mi][ni][j];
        if (EPI == 0) {
          if (n < Nw) {
            float t = v + bias[m];
            t = t > 0.f ? t : 0.01f * t;
            reinterpret_cast<unsigned short*>(Cp)[(size_t)m * ldc + n] =
                (n < N) ? f2bf(t) : (unsigned short)0;
          }
        } else {
          reinterpret_cast<float*>(Cp)[(size_t)z * pstride + (size_t)m * ldc + n] = v;
        }
      }
    }
  }
}

// f32 [rows,cols] -> bf16 [rowsPad,colsPad], zero-filled padding. cols % 8 == 0.
__global__ __launch_bounds__(256) void convert_kernel(
    const float* __restrict__ src, unsigned short* __restrict__ dst,
    int rows, int cols, int rowsPad, int colsPad)
{
  const int cpc = colsPad >> 3;
  const int nchunks = rowsPad * cpc;
  for (int idx = blockIdx.x * 256 + threadIdx.x; idx < nchunks; idx += gridDim.x * 256) {
    int row = idx / cpc;
    int c0  = (idx - row * cpc) << 3;
    u16x8 v = {};
    if (row < rows && c0 < cols) {
      const float* p = src + (size_t)row * cols + c0;
      f32x4 f0 = *reinterpret_cast<const f32x4*>(p);
      f32x4 f1 = *reinterpret_cast<const f32x4*>(p + 4);
      v[0] = f2bf(f0[0]); v[1] = f2bf(f0[1]); v[2] = f2bf(f0[2]); v[3] = f2bf(f0[3]);
      v[4] = f2bf(f1[0]); v[5] = f2bf(f1[1]); v[6] = f2bf(f1[2]); v[7] = f2bf(f1[3]);
    }
    *reinterpret_cast<u16x8*>(dst + (size_t)row * colsPad + c0) = v;
  }
}

// Per-row softmax stats + bf16 casts: xb = bf16(x), wb = bf16(softmax(x)), stride KPAD.
__global__ __launch_bounds__(256) void prep_x_kernel(
    const float* __restrict__ x,
    unsigned short* __restrict__ xb,
    unsigned short* __restrict__ wb)
{
  const int r = blockIdx.x;
  const int t = threadIdx.x;
  const float* xr = x + (size_t)r * INPUT;

  float m = -3.4e38f, s = 0.f;
  for (int c = t; c < INPUT / 4; c += 256) {
    float4 v = reinterpret_cast<const float4*>(xr)[c];
    float cm = fmaxf(fmaxf(v.x, v.y), fmaxf(v.z, v.w));
    if (cm > m) { s *= __expf(m - cm); m = cm; }
    s += __expf(v.x - m) + __expf(v.y - m) + __expf(v.z - m) + __expf(v.w - m);
  }
#pragma unroll
  for (int off = 32; off > 0; off >>= 1) {
    float om = __shfl_xor(m, off);
    float os = __shfl_xor(s, off);
    float nm = fmaxf(m, om);
    s = s * __expf(m - nm) + os * __expf(om - nm);
    m = nm;
  }
  __shared__ float sm[4], ss[4];
  if ((t & 63) == 0) { sm[t >> 6] = m; ss[t >> 6] = s; }
  __syncthreads();
  float M4 = fmaxf(fmaxf(sm[0], sm[1]), fmaxf(sm[2], sm[3]));
  float S4 = ss[0] * __expf(sm[0] - M4) + ss[1] * __expf(sm[1] - M4)
           + ss[2] * __expf(sm[2] - M4) + ss[3] * __expf(sm[3] - M4);
  float inv = 1.f / S4;

  unsigned short* xbr = xb + (size_t)r * KPAD;
  unsigned short* wbr = wb + (size_t)r * KPAD;
  for (int c = t; c < KPAD / 4; c += 256) {
    u16x4 xo = {}, wo = {};
    if (c < INPUT / 4) {
      float4 v = reinterpret_cast<const float4*>(xr)[c];
      xo[0] = f2bf(v.x); xo[1] = f2bf(v.y); xo[2] = f2bf(v.z); xo[3] = f2bf(v.w);
      wo[0] = f2bf(__expf(v.x - M4) * inv);
      wo[1] = f2bf(__expf(v.y - M4) * inv);
      wo[2] = f2bf(__expf(v.z - M4) * inv);
      wo[3] = f2bf(__expf(v.w - M4) * inv);
    }
    reinterpret_cast<u16x4*>(xbr)[c] = xo;
    reinterpret_cast<u16x4*>(wbr)[c] = wo;
  }
}

// Sum S split-K planes; MODE 0: combined buffer (b_ge+lrelu on cols<1024 only, bf16 out)
//                       MODE 1: final output (b_c+lrelu on all cols, f32 out)
template<int S, int MODE>
__global__ __launch_bounds__(256) void reduce_kernel(
    const float* __restrict__ P, const float* __restrict__ bias, void* __restrict__ outp)
{
  size_t base = ((size_t)blockIdx.x * 256 + threadIdx.x) * 4;
  f32x4 s = {};
#pragma unroll
  for (int zz = 0; zz < S; ++zz)
    s += *reinterpret_cast<const f32x4*>(P + (size_t)zz * BATCH * NOUT + base);
  int n = (int)(base & (NOUT - 1));
  if (MODE == 0) {
    u16x4 o;
    if (n < 1024) {
#pragma unroll
      for (int j = 0; j < 4; ++j) {
        float v = s[j] + bias[n + j];
        v = v > 0.f ? v : 0.01f * v;
        o[j] = f2bf(v);
      }
    } else {
#pragma unroll
      for (int j = 0; j < 4; ++j) o[j] = f2bf(s[j]);
    }
    *reinterpret_cast<u16x4*>(reinterpret_cast<unsigned short*>(outp) + base) = o;
  } else {
    f32x4 o;
#pragma unroll
    for (int j = 0; j < 4; ++j) {
      float v = s[j] + bias[n + j];
      o[j] = v > 0.f ? v : 0.01f * v;
    }
    *reinterpret_cast<f32x4*>(reinterpret_cast<float*>(outp) + base) = o;
  }
}

extern "C" void kernel_launch(void* const* d_in, const int* in_sizes, int n_in,
                              void* d_out, int out_size, void* d_ws, size_t ws_size,
                              hipStream_t stream)
{
  const float* x    = (const float*)d_in[0];
  const float* emb  = (const float*)d_in[1];
  const float* W_ge = (const float*)d_in[2];
  const float* b_ge = (const float*)d_in[3];
  const float* W_em = (const float*)d_in[4];
  const float* b_em = (const float*)d_in[5];
  const float* W_c  = (const float*)d_in[6];
  const float* b_c  = (const float*)d_in[7];
  float* out = (float*)d_out;

  char* ws = (char*)d_ws;
  unsigned short* xb   = (unsigned short*)(ws);                      // 512x20032 bf16  = 20,512,768
  unsigned short* wb   = (unsigned short*)(ws + 20512768);           // 20,512,768
  unsigned short* Wgeb = (unsigned short*)(ws + 41025536);           // 1024x20032 bf16 = 41,025,536
  unsigned short* Et   = (unsigned short*)(ws + 82051072);           // 1024x20032 bf16 = 41,025,536
  unsigned short* Wcb  = (unsigned short*)(ws + 123076608);          // 2048x2048 bf16  =  8,388,608
  unsigned short* comb = (unsigned short*)(ws + 131465216);          // 512x2048 bf16   =  2,097,152
  float*          P    = (float*)(ws + 133562368);                   // 16x512x2048 f32 = 67,108,864
  // embb/Wemb alias the P region (dead before P is first written)
  unsigned short* embb = (unsigned short*)(ws + 133562368);          // 20224x512 bf16  = 20,709,376
  unsigned short* Wemb = (unsigned short*)(ws + 133562368 + 20709376); // 1024x512 bf16 =  1,048,576
  // total ws usage: ~200.7 MB

  // 1) bf16 conversions (zero-padded)
  convert_kernel<<<1024, 256, 0, stream>>>(emb,  embb, INPUT, EMBED, NPADE, EMBED);
  convert_kernel<<<256,  256, 0, stream>>>(W_em, Wemb, HIDDEN, EMBED, HIDDEN, EMBED);
  convert_kernel<<<1024, 256, 0, stream>>>(W_ge, Wgeb, HIDDEN, INPUT, HIDDEN, KPAD);
  convert_kernel<<<512,  256, 0, stream>>>(W_c,  Wcb,  NOUT, NOUT, NOUT, NOUT);

  // 2) softmax stats + bf16 casts of x (stride KPAD, zero tail)
  prep_x_kernel<<<BATCH, 256, 0, stream>>>(x, xb, wb);

  // 3) Et[h,g] = lrelu(W_em @ emb^T + b_em): barrier-free streaming kernel.
  //    Grid 1280 (8 XCD x 16 m x 10 q; nidx>=79 return), 2 blocks/CU.
  et_stream<<<1280, 256, 0, stream>>>(Wemb, embb, b_em, Et);

  // 4) fused split-K partials: which=0: xb @ Wgeb^T -> cols 0..1023
  //                            which=1: wb @ Et^T   -> cols 1024..2047
  gemmQ<1><<<512, 256, 0, stream>>>(
      xb, Wgeb, wb, Et, KPAD, KPAD, nullptr,
      P, NOUT, 0, 0, KPAD, 1280);

  // 5) reduce 16 planes -> combined bf16 [512, 2048] (+b_ge+lrelu on first half)
  reduce_kernel<16, 0><<<(BATCH * NOUT / 4) / 256, 256, 0, stream>>>(P, b_ge, comb);

  // 6) combiner partials: comb @ Wcb^T (M=512, N=2048, K=2048, S=4)
  gemm97<1><<<dim3(16, 4, 4), 256, 0, stream>>>(
      comb, Wcb, NOUT, NOUT, nullptr,
      P, NOUT, BATCH * NOUT, BATCH, NOUT, NOUT, NOUT, 512);

  // 7) reduce 4 planes + b_c + lrelu -> f32 out [512, 2048]
  reduce_kernel<4, 1><<<(BATCH * NOUT / 4) / 256, 256, 0, stream>>>(P, b_c, out);
}

// Round 13
// 233.229 us; speedup vs baseline: 1.0206x; 1.0206x over previous
//
#include <hip/hip_runtime.h>
#include <hip/hip_bf16.h>
#include <stdint.h>

#define BATCH  512
#define INPUT  20000
#define KPAD   20032     // INPUT padded to multiple of 64 (zero tail)
#define KC_ALL 626       // KPAD / 32 chunks
#define NPADE  20224     // emb rows padded to multiple of 256 (zero-filled)
#define HIDDEN 1024
#define EMBED  512
#define NOUT   2048

typedef __attribute__((ext_vector_type(8))) __bf16 bf16x8;
typedef __attribute__((ext_vector_type(8))) unsigned short u16x8;
typedef __attribute__((ext_vector_type(4))) unsigned short u16x4;
typedef __attribute__((ext_vector_type(4))) float f32x4;

static __device__ __forceinline__ unsigned short f2bf(float f) {
  uint32_t u = __builtin_bit_cast(uint32_t, f);
  u += 0x7fffu + ((u >> 16) & 1u);          // round-to-nearest-even
  return (unsigned short)(u >> 16);
}

// async global->LDS (used by the small combiner GEMM)
static __device__ __forceinline__ void g2l16(const unsigned short* g, unsigned short* l) {
  __builtin_amdgcn_global_load_lds(
      (const __attribute__((address_space(1))) void*)g,
      (__attribute__((address_space(3))) void*)l, 16, 0, 0);
}

#define MFMA(a, b, c) __builtin_amdgcn_mfma_f32_16x16x32_bf16((a), (b), (c), 0, 0, 0)

// ====== 128x256-tile reg-staged GEMM on K-TILED operands ======
// Operands stored as [kchunk][R][32] bf16: each stage read is a CONTIGUOUS
// 8-16 KB block (2-4 sequential 4K pages, same pages for all lanes) instead of
// 128-256 sparse 40KB-strided rows -> collapses address-translation pressure,
// which is the only resource consistent with six structure-variants all
// pinning at 80-88 us with every PMC <17%.
// Inner loop identical to R11's verified gemmQ (LDS layout/swizzle/MFMA/epilogue).
// EPI 0 (Et): writes K-tiled bf16 Et_t[(n>>5)*1024 + m)*32 + (n&31)] with
//   lrelu(acc+bias[m]), zero for n in [Nv,Nw), skip n>=Nw.
// EPI 1 (fused34): f32 plane at Cp + z*BATCH*NOUT + m*NOUT + which*1024 + n.
// NEVER set min-waves > 2 here (R10: MW=4 halves the unified reg budget and
// spills acc[8][4] to scratch).
template<int EPI>
__global__ __launch_bounds__(256, 2) void gemmP(
    const unsigned short* __restrict__ A0p, const unsigned short* __restrict__ B0p,
    const unsigned short* __restrict__ A1p, const unsigned short* __restrict__ B1p,
    int RA, int RB,
    const float* __restrict__ bias,
    void* __restrict__ Cp,
    int Nv, int Nw, int KC, int CPZ)
{
  __shared__ __align__(16) unsigned short AsW[2 * 128 * 32];  // 16 KB
  __shared__ __align__(16) unsigned short BsW[2 * 256 * 32];  // 32 KB

  // ---- XCD-aware decode (hardware XCD = blockIdx % 8) ----
  const int b = blockIdx.x;
  int m0, n0, z = 0, which = 0;
  if (EPI == 1) {
    int g = ((b >> 7) << 3) | (b & 7);   // group (which,z) on XCD g%8
    int j = (b >> 3) & 15;
    which = g >> 4; z = g & 15;
    m0 = (j & 3) * 128;
    n0 = (j >> 2) * 256;
  } else {
    int xcd = b & 7, r = b >> 3;         // r 0..79
    int m = r / 10, q = r - m * 10;
    int nidx = xcd + 8 * q;
    if (nidx >= 79) return;
    m0 = m * 128;
    n0 = nidx * 256;
  }
  const unsigned short* Ap = which ? A1p : A0p;
  const unsigned short* Bp = which ? B1p : B0p;

  const int k0c = z * CPZ;
  const int nt  = min(CPZ, KC - k0c);

  const int tid = threadIdx.x;
  const int l = tid & 63, w = tid >> 6;
  const int srow = tid >> 2;             // 0..63
  const int sc8  = tid & 3;              // 16B chunk in 32-elem row
  const int swc = ((sc8 ^ ((srow >> 1) & 3)) << 3);   // swizzled LDS col

  const size_t pa = (size_t)RA * 32, pb = (size_t)RB * 32;  // plane strides
  const unsigned short* agl = Ap + (size_t)k0c * pa + (m0 + srow) * 32 + sc8 * 8;
  const unsigned short* bgl = Bp + (size_t)k0c * pb + (n0 + srow) * 32 + sc8 * 8;

  const int lr = l & 15, lkc = l >> 4;
  const int ck = ((lkc ^ ((lr >> 1) & 3)) << 3);      // swizzled read col

  f32x4 acc[8][4] = {};
  u16x8 ra0, ra1, rb0, rb1, rb2, rb3;    // named depth-1 staging (rule #20)

#define LOADT(ct)                                                               \
  do {                                                                          \
    const unsigned short* ab = agl + (size_t)(ct) * pa;                         \
    const unsigned short* bb = bgl + (size_t)(ct) * pb;                         \
    ra0 = *reinterpret_cast<const u16x8*>(ab);                                  \
    ra1 = *reinterpret_cast<const u16x8*>(ab + 64 * 32);                        \
    rb0 = *reinterpret_cast<const u16x8*>(bb);                                  \
    rb1 = *reinterpret_cast<const u16x8*>(bb + 64 * 32);                        \
    rb2 = *reinterpret_cast<const u16x8*>(bb + 128 * 32);                       \
    rb3 = *reinterpret_cast<const u16x8*>(bb + 192 * 32);                       \
  } while (0)

#define WRITET(BUF)                                                             \
  do {                                                                          \
    *reinterpret_cast<u16x8*>(AsW + (BUF)*4096 + (srow      ) * 32 + swc) = ra0; \
    *reinterpret_cast<u16x8*>(AsW + (BUF)*4096 + (srow +  64) * 32 + swc) = ra1; \
    *reinterpret_cast<u16x8*>(BsW + (BUF)*8192 + (srow      ) * 32 + swc) = rb0; \
    *reinterpret_cast<u16x8*>(BsW + (BUF)*8192 + (srow +  64) * 32 + swc) = rb1; \
    *reinterpret_cast<u16x8*>(BsW + (BUF)*8192 + (srow + 128) * 32 + swc) = rb2; \
    *reinterpret_cast<u16x8*>(BsW + (BUF)*8192 + (srow + 192) * 32 + swc) = rb3; \
  } while (0)

  LOADT(0);
  WRITET(0);
  __syncthreads();

  for (int t = 0; t < nt; ++t) {
    const int buf = t & 1, nb = buf ^ 1;
    if (t + 1 < nt) LOADT(t + 1);
    __builtin_amdgcn_sched_barrier(0);

    bf16x8 a[8], bfr[4];
#pragma unroll
    for (int mi = 0; mi < 8; ++mi)
      a[mi] = *reinterpret_cast<const bf16x8*>(AsW + buf * 4096 + (mi * 16 + lr) * 32 + ck);
#pragma unroll
    for (int ni = 0; ni < 4; ++ni)
      bfr[ni] = *reinterpret_cast<const bf16x8*>(
          BsW + buf * 8192 + (w * 64 + ni * 16 + lr) * 32 + ck);

    __builtin_amdgcn_s_setprio(1);
#pragma unroll
    for (int mi = 0; mi < 8; ++mi)
#pragma unroll
      for (int ni = 0; ni < 4; ++ni)
        acc[mi][ni] = MFMA(a[mi], bfr[ni], acc[mi][ni]);
    __builtin_amdgcn_s_setprio(0);

    if (t + 1 < nt) WRITET(nb);
    __syncthreads();
  }
#undef LOADT
#undef WRITET

  // C/D layout: col = lane&15, row = (lane>>4)*4 + reg  [m89/m91]
  const int rb_ = (l >> 4) * 4;
#pragma unroll
  for (int mi = 0; mi < 8; ++mi)
#pragma unroll
    for (int ni = 0; ni < 4; ++ni)
#pragma unroll
      for (int j = 0; j < 4; ++j) {
        int m = m0 + mi * 16 + rb_ + j;
        int n = n0 + w * 64 + ni * 16 + lr;
        float v = acc[mi][ni][j];
        if (EPI == 0) {
          if (n < Nw) {
            float t2 = v + bias[m];
            t2 = t2 > 0.f ? t2 : 0.01f * t2;
            reinterpret_cast<unsigned short*>(Cp)[
                ((size_t)(n >> 5) * HIDDEN + m) * 32 + (n & 31)] =
                (n < Nv) ? f2bf(t2) : (unsigned short)0;
          }
        } else {
          reinterpret_cast<float*>(Cp)[(size_t)z * (BATCH * NOUT) + (size_t)m * NOUT +
                                       which * 1024 + n] = v;
        }
      }
}

// ===== 128x128-tile m97-style GEMM (combiner only; small linear operands) =====
template<int EPI>
__global__ __launch_bounds__(256) void gemm97(
    const unsigned short* __restrict__ A, const unsigned short* __restrict__ B,
    int lda, int ldb,
    const float* __restrict__ bias,
    void* __restrict__ Cp, int ldc, int pstride,
    int M, int N, int Nw, int K, int kChunk)
{
  __shared__ __align__(16) unsigned short As[128 * 64];
  __shared__ __align__(16) unsigned short Bs[128 * 64];

  const int z = blockIdx.z;
  const int m0 = blockIdx.y * 128, n0 = blockIdx.x * 128;
  const int k0   = z * kChunk;
  const int kend = min(K, k0 + kChunk);
  const int tid = threadIdx.x;
  const int l = tid & 63, w = tid >> 6;

  const int srow = w * 32 + (l >> 3);
  const int scol = (l & 7) * 8;
  const unsigned short* ag = A + (size_t)(m0 + srow) * lda + scol;
  const unsigned short* bg = B + (size_t)(n0 + srow) * ldb + scol;

  const int wm = (w >> 1) * 64, wn = (w & 1) * 64;
  const int lr = l & 15, lk = (l >> 4) * 8;

  f32x4 acc[4][4] = {};

  for (int kb = k0; kb < kend; kb += 64) {
#pragma unroll
    for (int j = 0; j < 4; ++j)
      g2l16(ag + (size_t)j * 8 * lda + kb, As + (w * 32 + j * 8) * 64);
#pragma unroll
    for (int j = 0; j < 4; ++j)
      g2l16(bg + (size_t)j * 8 * ldb + kb, Bs + (w * 32 + j * 8) * 64);
    __syncthreads();
#pragma unroll
    for (int ks = 0; ks < 2; ++ks) {
      bf16x8 a[4], b2[4];
#pragma unroll
      for (int i = 0; i < 4; ++i)
        a[i] = *reinterpret_cast<const bf16x8*>(&As[(wm + i * 16 + lr) * 64 + ks * 32 + lk]);
#pragma unroll
      for (int i = 0; i < 4; ++i)
        b2[i] = *reinterpret_cast<const bf16x8*>(&Bs[(wn + i * 16 + lr) * 64 + ks * 32 + lk]);
#pragma unroll
      for (int mi = 0; mi < 4; ++mi)
#pragma unroll
        for (int ni = 0; ni < 4; ++ni)
          acc[mi][ni] = MFMA(a[mi], b2[ni], acc[mi][ni]);
    }
    __syncthreads();
  }

  const int rb = (l >> 4) * 4;
#pragma unroll
  for (int mi = 0; mi < 4; ++mi) {
#pragma unroll
    for (int ni = 0; ni < 4; ++ni) {
#pragma unroll
      for (int j = 0; j < 4; ++j) {
        int m = m0 + wm + mi * 16 + rb + j;
        int n = n0 + wn + ni * 16 + lr;
        float v = acc[mi][ni][j];
        if (EPI == 0) {
          if (n < Nw) {
            float t = v + bias[m];
            t = t > 0.f ? t : 0.01f * t;
            reinterpret_cast<unsigned short*>(Cp)[(size_t)m * ldc + n] =
                (n < N) ? f2bf(t) : (unsigned short)0;
          }
        } else {
          reinterpret_cast<float*>(Cp)[(size_t)z * pstride + (size_t)m * ldc + n] = v;
        }
      }
    }
  }
}

// f32 [rows,cols] -> bf16 K-TILED [kchunk][rowsPad][32], zero-filled padding.
__global__ __launch_bounds__(256) void convert_tiled_kernel(
    const float* __restrict__ src, unsigned short* __restrict__ dst,
    int rows, int cols, int rowsPad, int colsPad)
{
  const int cpc = colsPad >> 3;             // 8-elem groups per row
  const int nchunks = rowsPad * cpc;
  for (int idx = blockIdx.x * 256 + threadIdx.x; idx < nchunks; idx += gridDim.x * 256) {
    int row = idx / cpc;
    int c8  = idx - row * cpc;
    int c0  = c8 << 3;
    u16x8 v = {};
    if (row < rows && c0 < cols) {
      const float* p = src + (size_t)row * cols + c0;
      f32x4 f0 = *reinterpret_cast<const f32x4*>(p);
      f32x4 f1 = *reinterpret_cast<const f32x4*>(p + 4);
      v[0] = f2bf(f0[0]); v[1] = f2bf(f0[1]); v[2] = f2bf(f0[2]); v[3] = f2bf(f0[3]);
      v[4] = f2bf(f1[0]); v[5] = f2bf(f1[1]); v[6] = f2bf(f1[2]); v[7] = f2bf(f1[3]);
    }
    // tiled: [c0>>5][row][c0&31]
    *reinterpret_cast<u16x8*>(dst + ((size_t)(c0 >> 5) * rowsPad + row) * 32 + (c0 & 31)) = v;
  }
}

// f32 [rows,cols] -> bf16 linear [rowsPad,colsPad] (combiner weights)
__global__ __launch_bounds__(256) void convert_kernel(
    const float* __restrict__ src, unsigned short* __restrict__ dst,
    int rows, int cols, int rowsPad, int colsPad)
{
  const int cpc = colsPad >> 3;
  const int nchunks = rowsPad * cpc;
  for (int idx = blockIdx.x * 256 + threadIdx.x; idx < nchunks; idx += gridDim.x * 256) {
    int row = idx / cpc;
    int c0  = (idx - row * cpc) << 3;
    u16x8 v = {};
    if (row < rows && c0 < cols) {
      const float* p = src + (size_t)row * cols + c0;
      f32x4 f0 = *reinterpret_cast<const f32x4*>(p);
      f32x4 f1 = *reinterpret_cast<const f32x4*>(p + 4);
      v[0] = f2bf(f0[0]); v[1] = f2bf(f0[1]); v[2] = f2bf(f0[2]); v[3] = f2bf(f0[3]);
      v[4] = f2bf(f1[0]); v[5] = f2bf(f1[1]); v[6] = f2bf(f1[2]); v[7] = f2bf(f1[3]);
    }
    *reinterpret_cast<u16x8*>(dst + (size_t)row * colsPad + c0) = v;
  }
}

// Per-row softmax stats + bf16 casts, K-TILED outputs:
// xb_t/wb_t[(c0>>5)*BATCH + r)*32 + (c0&31)]
__global__ __launch_bounds__(256) void prep_x_kernel(
    const float* __restrict__ x,
    unsigned short* __restrict__ xb,
    unsigned short* __restrict__ wb)
{
  const int r = blockIdx.x;
  const int t = threadIdx.x;
  const float* xr = x + (size_t)r * INPUT;

  float m = -3.4e38f, s = 0.f;
  for (int c = t; c < INPUT / 4; c += 256) {
    float4 v = reinterpret_cast<const float4*>(xr)[c];
    float cm = fmaxf(fmaxf(v.x, v.y), fmaxf(v.z, v.w));
    if (cm > m) { s *= __expf(m - cm); m = cm; }
    s += __expf(v.x - m) + __expf(v.y - m) + __expf(v.z - m) + __expf(v.w - m);
  }
#pragma unroll
  for (int off = 32; off > 0; off >>= 1) {
    float om = __shfl_xor(m, off);
    float os = __shfl_xor(s, off);
    float nm = fmaxf(m, om);
    s = s * __expf(m - nm) + os * __expf(om - nm);
    m = nm;
  }
  __shared__ float sm[4], ss[4];
  if ((t & 63) == 0) { sm[t >> 6] = m; ss[t >> 6] = s; }
  __syncthreads();
  float M4 = fmaxf(fmaxf(sm[0], sm[1]), fmaxf(sm[2], sm[3]));
  float S4 = ss[0] * __expf(sm[0] - M4) + ss[1] * __expf(sm[1] - M4)
           + ss[2] * __expf(sm[2] - M4) + ss[3] * __expf(sm[3] - M4);
  float inv = 1.f / S4;

  for (int c8 = t; c8 < KPAD / 8; c8 += 256) {
    int c0 = c8 << 3;
    u16x8 xo = {}, wo = {};
    if (c0 < INPUT) {
      const float* p = xr + c0;
      f32x4 f0 = *reinterpret_cast<const f32x4*>(p);
      f32x4 f1 = *reinterpret_cast<const f32x4*>(p + 4);
#pragma unroll
      for (int j = 0; j < 4; ++j) {
        xo[j]     = f2bf(f0[j]);
        xo[j + 4] = f2bf(f1[j]);
        wo[j]     = f2bf(__expf(f0[j] - M4) * inv);
        wo[j + 4] = f2bf(__expf(f1[j] - M4) * inv);
      }
    }
    size_t off = ((size_t)(c0 >> 5) * BATCH + r) * 32 + (c0 & 31);
    *reinterpret_cast<u16x8*>(xb + off) = xo;
    *reinterpret_cast<u16x8*>(wb + off) = wo;
  }
}

// Sum S split-K planes; MODE 0: combined buffer (b_ge+lrelu on cols<1024 only, bf16 out)
//                       MODE 1: final output (b_c+lrelu on all cols, f32 out)
template<int S, int MODE>
__global__ __launch_bounds__(256) void reduce_kernel(
    const float* __restrict__ P, const float* __restrict__ bias, void* __restrict__ outp)
{
  size_t base = ((size_t)blockIdx.x * 256 + threadIdx.x) * 4;
  f32x4 s = {};
#pragma unroll
  for (int zz = 0; zz < S; ++zz)
    s += *reinterpret_cast<const f32x4*>(P + (size_t)zz * BATCH * NOUT + base);
  int n = (int)(base & (NOUT - 1));
  if (MODE == 0) {
    u16x4 o;
    if (n < 1024) {
#pragma unroll
      for (int j = 0; j < 4; ++j) {
        float v = s[j] + bias[n + j];
        v = v > 0.f ? v : 0.01f * v;
        o[j] = f2bf(v);
      }
    } else {
#pragma unroll
      for (int j = 0; j < 4; ++j) o[j] = f2bf(s[j]);
    }
    *reinterpret_cast<u16x4*>(reinterpret_cast<unsigned short*>(outp) + base) = o;
  } else {
    f32x4 o;
#pragma unroll
    for (int j = 0; j < 4; ++j) {
      float v = s[j] + bias[n + j];
      o[j] = v > 0.f ? v : 0.01f * v;
    }
    *reinterpret_cast<f32x4*>(reinterpret_cast<float*>(outp) + base) = o;
  }
}

extern "C" void kernel_launch(void* const* d_in, const int* in_sizes, int n_in,
                              void* d_out, int out_size, void* d_ws, size_t ws_size,
                              hipStream_t stream)
{
  const float* x    = (const float*)d_in[0];
  const float* emb  = (const float*)d_in[1];
  const float* W_ge = (const float*)d_in[2];
  const float* b_ge = (const float*)d_in[3];
  const float* W_em = (const float*)d_in[4];
  const float* b_em = (const float*)d_in[5];
  const float* W_c  = (const float*)d_in[6];
  const float* b_c  = (const float*)d_in[7];
  float* out = (float*)d_out;

  char* ws = (char*)d_ws;
  // K-tiled buffers [kchunk][R][32]:
  unsigned short* xb_t   = (unsigned short*)(ws);                     // 626x512x32   = 20,512,768
  unsigned short* wb_t   = (unsigned short*)(ws + 20512768);          // 20,512,768
  unsigned short* Wgeb_t = (unsigned short*)(ws + 41025536);          // 626x1024x32  = 41,025,536
  unsigned short* Et_t   = (unsigned short*)(ws + 82051072);          // 626x1024x32  = 41,025,536
  unsigned short* Wcb    = (unsigned short*)(ws + 123076608);         // 2048x2048    =  8,388,608 (linear)
  unsigned short* comb   = (unsigned short*)(ws + 131465216);         // 512x2048     =  2,097,152 (linear)
  float*          P      = (float*)(ws + 133562368);                  // 16x512x2048 f32 = 67,108,864
  // embb_t/Wemb_t alias the P region (dead before P is first written)
  unsigned short* embb_t = (unsigned short*)(ws + 133562368);         // 16x20224x32  = 20,709,376
  unsigned short* Wemb_t = (unsigned short*)(ws + 133562368 + 20709376); // 16x1024x32 = 1,048,576

  // 1) bf16 conversions (K-tiled, zero-padded)
  convert_tiled_kernel<<<1024, 256, 0, stream>>>(emb,  embb_t, INPUT, EMBED, NPADE, EMBED);
  convert_tiled_kernel<<<256,  256, 0, stream>>>(W_em, Wemb_t, HIDDEN, EMBED, HIDDEN, EMBED);
  convert_tiled_kernel<<<1024, 256, 0, stream>>>(W_ge, Wgeb_t, HIDDEN, INPUT, HIDDEN, KPAD);
  convert_kernel<<<512,  256, 0, stream>>>(W_c, Wcb, NOUT, NOUT, NOUT, NOUT);

  // 2) softmax stats + bf16 casts of x -> K-tiled xb_t, wb_t
  prep_x_kernel<<<BATCH, 256, 0, stream>>>(x, xb_t, wb_t);

  // 3) Et_t[h,g] = lrelu(W_em @ emb^T + b_em), K-tiled output.
  //    Grid 640 (8 XCD x 8 m x 10 q; nidx>=79 return), 2 blocks/CU.
  gemmP<0><<<640, 256, 0, stream>>>(
      Wemb_t, embb_t, nullptr, nullptr, HIDDEN, NPADE, b_em,
      Et_t, INPUT, KPAD, 16, 16);

  // 4) fused split-K partials on K-tiled operands:
  //    which=0: xb_t @ Wgeb_t^T -> cols 0..1023 ; which=1: wb_t @ Et_t^T -> 1024..2047
  gemmP<1><<<512, 256, 0, stream>>>(
      xb_t, Wgeb_t, wb_t, Et_t, BATCH, HIDDEN, nullptr,
      P, 0, 0, KC_ALL, 40);

  // 5) reduce 16 planes -> combined bf16 [512, 2048] (+b_ge+lrelu on first half)
  reduce_kernel<16, 0><<<(BATCH * NOUT / 4) / 256, 256, 0, stream>>>(P, b_ge, comb);

  // 6) combiner partials: comb @ Wcb^T (M=512, N=2048, K=2048, S=4)
  gemm97<1><<<dim3(16, 4, 4), 256, 0, stream>>>(
      comb, Wcb, NOUT, NOUT, nullptr,
      P, NOUT, BATCH * NOUT, BATCH, NOUT, NOUT, NOUT, 512);

  // 7) reduce 4 planes + b_c + lrelu -> f32 out [512, 2048]
  reduce_kernel<4, 1><<<(BATCH * NOUT / 4) / 256, 256, 0, stream>>>(P, b_c, out);
}